// Round 4
// baseline (440.911 us; speedup 1.0000x reference)
//
#include <hip/hip_runtime.h>
#include <hip/hip_bf16.h>
#include <cstdint>

#define T_  4096
#define H_  1024
#define E_  16
#define MI_ 512
#define SI_ 2048
#define TK_ 8192   // T_ * K(=2)

typedef __bf16 bf16;
typedef bf16  bf16x8 __attribute__((ext_vector_type(8)));
typedef bf16  bf16x4 __attribute__((ext_vector_type(4)));
typedef float f32x4  __attribute__((ext_vector_type(4)));

// async global->LDS, 16B per lane. LDS dest = wave-uniform base + lane*16.
__device__ __forceinline__ void gload16(const bf16* g, bf16* lds) {
    __builtin_amdgcn_global_load_lds(
        (const __attribute__((address_space(1))) void*)(uintptr_t)(const void*)g,
        (__attribute__((address_space(3))) void*)(uintptr_t)(void*)lds,
        16, 0, 0);
}

// ---------------- fp32 -> bf16 flat convert (vectorized) ----------------
__global__ void k_convert(const float* __restrict__ src, bf16* __restrict__ dst, int n4) {
    int i = blockIdx.x * blockDim.x + threadIdx.x;
    if (i < n4) {
        float4 v = reinterpret_cast<const float4*>(src)[i];
        bf16x4 o;
        o[0] = (bf16)v.x; o[1] = (bf16)v.y; o[2] = (bf16)v.z; o[3] = (bf16)v.w;
        reinterpret_cast<bf16x4*>(dst)[i] = o;
    }
}

// ---------------- fp32 [R][C] -> bf16 [C][R] transpose (per z-slice) ----------------
__global__ void k_transpose(const float* __restrict__ src, bf16* __restrict__ dst, int R, int C) {
    __shared__ float tile[32][33];
    size_t zoff = (size_t)blockIdx.z * (size_t)R * (size_t)C;
    src += zoff; dst += zoff;
    int c  = blockIdx.x * 32 + threadIdx.x;
    #pragma unroll
    for (int i = 0; i < 4; i++) {
        int r = blockIdx.y * 32 + threadIdx.y + i * 8;
        tile[threadIdx.y + i * 8][threadIdx.x] = src[(size_t)r * C + c];
    }
    __syncthreads();
    int rr = blockIdx.y * 32 + threadIdx.x;   // original row -> new col
    #pragma unroll
    for (int i = 0; i < 4; i++) {
        int cc = blockIdx.x * 32 + threadIdx.y + i * 8;  // original col -> new row
        dst[(size_t)cc * R + rr] = (bf16)tile[threadIdx.x][threadIdx.y + i * 8];
    }
}

// ---------------- router: logits (fp32), top-2, shared gate scalar. NO atomics. ----------------
__global__ __launch_bounds__(256) void k_router(
    const float* __restrict__ x, const float* __restrict__ rw,
    const float* __restrict__ segw, float* __restrict__ logits_out,
    int* __restrict__ top_i, float* __restrict__ top_w,
    float* __restrict__ gate_scalar)
{
    int wid = threadIdx.x >> 6, lane = threadIdx.x & 63;
    int t = blockIdx.x * 4 + wid;
    const float* xr = x + (size_t)t * H_;
    float acc[E_];
    #pragma unroll
    for (int e = 0; e < E_; e++) acc[e] = 0.f;
    float accg = 0.f;
    for (int j = 0; j < H_ / 64; j++) {
        int h = j * 64 + lane;
        float xv = xr[h];
        const float4* wrow = reinterpret_cast<const float4*>(rw + (size_t)h * E_);
        #pragma unroll
        for (int q = 0; q < 4; q++) {
            float4 w4 = wrow[q];
            acc[q*4+0] += xv * w4.x; acc[q*4+1] += xv * w4.y;
            acc[q*4+2] += xv * w4.z; acc[q*4+3] += xv * w4.w;
        }
        accg += xv * segw[h];
    }
    #pragma unroll
    for (int off = 32; off >= 1; off >>= 1) {
        #pragma unroll
        for (int e = 0; e < E_; e++) acc[e] += __shfl_xor(acc[e], off);
        accg += __shfl_xor(accg, off);
    }
    if (lane == 0) {
        float* lo = logits_out + (size_t)t * E_;
        #pragma unroll
        for (int e = 0; e < E_; e++) lo[e] = acc[e];
        int i0 = 0; float l0 = acc[0];
        #pragma unroll
        for (int e = 1; e < E_; e++) if (acc[e] > l0) { l0 = acc[e]; i0 = e; }
        int i1 = -1; float l1 = -1e30f;
        #pragma unroll
        for (int e = 0; e < E_; e++) if (e != i0 && acc[e] > l1) { l1 = acc[e]; i1 = e; }
        float w0 = 1.f / (1.f + expf(l1 - l0));   // p0/(p0+p1)
        top_i[t*2] = i0; top_i[t*2+1] = i1;
        top_w[t*2] = w0; top_w[t*2+1] = 1.f - w0;
        gate_scalar[t] = 1.f / (1.f + expf(-accg));
    }
}

// ---------------- counts + offsets from top_i, single block, no global atomics ----------------
__global__ __launch_bounds__(256) void k_count(const int* __restrict__ top_i, int* __restrict__ offsets) {
    __shared__ int hist[256][17];
    int tid = threadIdx.x;
    #pragma unroll
    for (int e = 0; e < E_; e++) hist[tid][e] = 0;
    __syncthreads();
    const int* mine = top_i + tid * 32;
    #pragma unroll
    for (int j = 0; j < 32; j++) hist[tid][mine[j]]++;
    __syncthreads();
    if (tid < E_) {
        int s = 0;
        for (int r = 0; r < 256; r++) s += hist[r][tid];
        hist[0][tid] = s;
    }
    __syncthreads();
    if (tid == 0) {
        int s = 0;
        for (int e = 0; e < E_; e++) { offsets[e] = s; s += hist[0][e]; }
        offsets[E_] = s;
    }
}

// ---------------- deterministic slot assignment by rank (prefix scan), one block per expert ----------------
__global__ __launch_bounds__(256) void k_fillscan(
    const int* __restrict__ top_i, const int* __restrict__ offsets,
    int* __restrict__ slot_token, int* __restrict__ slot_pos)
{
    int e = blockIdx.x;
    int tid = threadIdx.x;
    int lane = tid & 63, w = tid >> 6;
    __shared__ int wsum[4];

    int t0 = tid * 16;
    unsigned f0 = 0, f1 = 0;
    int c = 0;
    #pragma unroll
    for (int j = 0; j < 16; j++) {
        int t = t0 + j;
        int a = top_i[t*2], b = top_i[t*2+1];
        if (a == e)      { f0 |= 1u << j; c++; }
        else if (b == e) { f1 |= 1u << j; c++; }
    }
    int incl = c;
    #pragma unroll
    for (int off = 1; off < 64; off <<= 1) {
        int v = __shfl_up(incl, off);
        if (lane >= off) incl += v;
    }
    if (lane == 63) wsum[w] = incl;
    __syncthreads();
    int wbase = 0;
    for (int i = 0; i < w; i++) wbase += wsum[i];
    int pos = offsets[e] + wbase + (incl - c);
    #pragma unroll
    for (int j = 0; j < 16; j++) {
        int t = t0 + j;
        if ((f0 >> j) & 1u)      { slot_token[pos] = t; slot_pos[t*2]   = pos; pos++; }
        else if ((f1 >> j) & 1u) { slot_token[pos] = t; slot_pos[t*2+1] = pos; pos++; }
    }
}

// ---------------- unified GEMM: prefetched 2-phase double-buffered (T3 minimum recipe) ----------------
// MODE 0: expert gate/up + silu-mul -> hiddenE (bf16), A = xb gathered via slot_token, K=1024
// MODE 1: shared gate/up + silu-mul -> sh_hid (bf16), K=1024
// MODE 2: expert down -> eo (bf16), A = hiddenE (slot rows), K=512
// MODE 3: shared down -> d_out (f32, * gate_s), A = sh_hid, K=2048
// Tile: 128 rows x (GU: 64 paired cols / DOWN: 128 cols), BK=32, 256 threads.
template<int MODE, int KDIM>
__global__ __launch_bounds__(256) void k_gemm(
    const bf16* __restrict__ A, const bf16* __restrict__ Bbase, const bf16* __restrict__ Bbase2,
    const int* __restrict__ slot_token, const int* __restrict__ offsets,
    const float* __restrict__ gate_s,
    bf16* __restrict__ out_bf, float* __restrict__ out_f32)
{
    constexpr bool EXPERT = (MODE == 0 || MODE == 2);
    constexpr bool GU     = (MODE <= 1);
    int e = blockIdx.z;
    int base = EXPERT ? offsets[e] : 0;
    int cnt  = EXPERT ? offsets[e+1] - base : T_;

    // bijective XCD swizzle over the (x,y) plane (plane size is a multiple of 8)
    int nwg = gridDim.x * gridDim.y;
    int p   = blockIdx.y * gridDim.x + blockIdx.x;
    int swz = (p & 7) * (nwg >> 3) + (p >> 3);
    int nt = swz % gridDim.x, mt = swz / gridDim.x;
    if (mt * 128 >= cnt) return;

    const bf16 *B0, *B1;
    if (MODE == 0) {
        const bf16* wb = Bbase + (size_t)e * (2 * MI_) * H_;
        B0 = wb + (size_t)(nt * 64) * KDIM;
        B1 = wb + (size_t)(MI_ + nt * 64) * KDIM;
    } else if (MODE == 1) {
        B0 = Bbase  + (size_t)(nt * 64) * KDIM;
        B1 = Bbase2 + (size_t)(nt * 64) * KDIM;
    } else if (MODE == 2) {
        const bf16* wb = Bbase + (size_t)e * H_ * MI_;
        B0 = wb + (size_t)(nt * 128) * KDIM;
        B1 = B0 + (size_t)64 * KDIM;
    } else {
        B0 = Bbase + (size_t)(nt * 128) * KDIM;
        B1 = B0 + (size_t)64 * KDIM;
    }

    __shared__ __align__(16) bf16 As[2][128 * 32];
    __shared__ __align__(16) bf16 Bs[2][128 * 32];

    int tid = threadIdx.x, w = tid >> 6, l = tid & 63;
    int srow = l >> 2;            // 0..15
    int scol = (l & 3) * 8;       // bf16 elems (16B chunks)

    // per-lane global source pointers (fixed across k-loop)
    const bf16* asrc[2];
    const bf16* bsrc[2];
    #pragma unroll
    for (int i = 0; i < 2; i++) {
        int r = i * 64 + w * 16 + srow;         // row within 128-tile
        if (MODE == 0) {
            int s = mt * 128 + r; if (s >= cnt) s = cnt - 1;
            asrc[i] = A + (size_t)slot_token[base + s] * KDIM + scol;
        } else if (MODE == 2) {
            int s = mt * 128 + r; if (s >= cnt) s = cnt - 1;
            asrc[i] = A + (size_t)(base + s) * KDIM + scol;
        } else {
            asrc[i] = A + (size_t)(mt * 128 + r) * KDIM + scol;
        }
        bsrc[i] = (r < 64 ? B0 + (size_t)r * KDIM : B1 + (size_t)(r - 64) * KDIM) + scol;
    }
    // wave-uniform LDS staging bases (HW adds lane*16B)
    int a_off0 = (0  + w * 16) * 32;
    int a_off1 = (64 + w * 16) * 32;

    int lr = l & 15, kq = l >> 4;
    f32x4 acc[2][8];
    #pragma unroll
    for (int mi = 0; mi < 2; mi++)
        #pragma unroll
        for (int ni = 0; ni < 8; ni++) acc[mi][ni] = (f32x4){0.f, 0.f, 0.f, 0.f};

    auto STAGE = [&](int b, int k0) {
        gload16(asrc[0] + k0, &As[b][a_off0]);
        gload16(asrc[1] + k0, &As[b][a_off1]);
        gload16(bsrc[0] + k0, &Bs[b][a_off0]);
        gload16(bsrc[1] + k0, &Bs[b][a_off1]);
    };
    auto COMPUTE = [&](int b) {
        bf16x8 af[2], bfr[8];
        #pragma unroll
        for (int mi = 0; mi < 2; mi++)
            af[mi] = *reinterpret_cast<const bf16x8*>(&As[b][(w * 32 + mi * 16 + lr) * 32 + kq * 8]);
        #pragma unroll
        for (int ni = 0; ni < 8; ni++)
            bfr[ni] = *reinterpret_cast<const bf16x8*>(&Bs[b][(ni * 16 + lr) * 32 + kq * 8]);
        #pragma unroll
        for (int mi = 0; mi < 2; mi++)
            #pragma unroll
            for (int ni = 0; ni < 8; ni++)
                acc[mi][ni] = __builtin_amdgcn_mfma_f32_16x16x32_bf16(af[mi], bfr[ni], acc[mi][ni], 0, 0, 0);
    };

    // prologue: stage tile 0, drain, raw barrier
    STAGE(0, 0);
    asm volatile("s_waitcnt vmcnt(0)" ::: "memory");
    asm volatile("s_barrier" ::: "memory");

    int cur = 0;
    for (int k0 = 32; k0 < KDIM; k0 += 32) {
        STAGE(cur ^ 1, k0);          // prefetch next tile (in flight during compute)
        COMPUTE(cur);                // ds_read + MFMA on current tile
        asm volatile("s_waitcnt vmcnt(0)" ::: "memory");   // prefetch landed
        asm volatile("s_barrier" ::: "memory");
        cur ^= 1;
    }
    COMPUTE(cur);                    // last tile, no prefetch

    // epilogue: D row = A_row_base + kq*4 + r, col = B_row_base + lr (m89-verified)
    #pragma unroll
    for (int mi = 0; mi < 2; mi++)
        #pragma unroll
        for (int ni = 0; ni < (GU ? 4 : 8); ni++)
            #pragma unroll
            for (int r = 0; r < 4; r++) {
                int row = mt * 128 + w * 32 + mi * 16 + kq * 4 + r;
                if (row < cnt) {
                    if (GU) {
                        constexpr int NOUT = (MODE == 0) ? MI_ : SI_;
                        int col = nt * 64 + ni * 16 + lr;
                        float g = acc[mi][ni][r], u = acc[mi][ni + 4][r];
                        float hv = u * (g / (1.f + expf(-g)));
                        out_bf[(size_t)(base + row) * NOUT + col] = (bf16)hv;
                    } else {
                        int col = nt * 128 + ni * 16 + lr;
                        float v = acc[mi][ni][r];
                        if (MODE == 2) out_bf[(size_t)(base + row) * H_ + col] = (bf16)v;
                        else           out_f32[(size_t)row * H_ + col] = gate_s[row] * v;
                    }
                }
            }
}

// ---------------- combine: out += w0*eo[s0] + w1*eo[s1] ----------------
__global__ void k_combine(float* __restrict__ out, const bf16* __restrict__ eo,
                          const int* __restrict__ slot_pos, const float* __restrict__ top_w)
{
    int i = blockIdx.x * blockDim.x + threadIdx.x;
    int t = i >> 8;
    int q = (i & 255) * 4;
    int s0 = slot_pos[t*2], s1 = slot_pos[t*2+1];
    float w0 = top_w[t*2], w1 = top_w[t*2+1];
    bf16x4 e0 = *reinterpret_cast<const bf16x4*>(eo + (size_t)s0 * H_ + q);
    bf16x4 e1 = *reinterpret_cast<const bf16x4*>(eo + (size_t)s1 * H_ + q);
    float4* op = reinterpret_cast<float4*>(out) + i;
    float4 so = *op;
    float4 r;
    r.x = so.x + w0 * (float)e0[0] + w1 * (float)e1[0];
    r.y = so.y + w0 * (float)e0[1] + w1 * (float)e1[1];
    r.z = so.z + w0 * (float)e0[2] + w1 * (float)e1[2];
    r.w = so.w + w0 * (float)e0[3] + w1 * (float)e1[3];
    *op = r;
}

extern "C" void kernel_launch(void* const* d_in, const int* in_sizes, int n_in,
                              void* d_out, int out_size, void* d_ws, size_t ws_size,
                              hipStream_t stream) {
    const float* x    = (const float*)d_in[0];
    const float* rw   = (const float*)d_in[1];
    const float* wgu  = (const float*)d_in[2];
    const float* wdn  = (const float*)d_in[3];
    const float* wsg  = (const float*)d_in[4];
    const float* wsu  = (const float*)d_in[5];
    const float* wsd  = (const float*)d_in[6];
    const float* segw = (const float*)d_in[7];
    float* out    = (float*)d_out;
    float* logits = (float*)d_out + (size_t)T_ * H_;

    char* p = (char*)d_ws;
    bf16* xb      = (bf16*)p;  p += (size_t)T_ * H_ * 2;
    bf16* w_guT   = (bf16*)p;  p += (size_t)E_ * H_ * (2*MI_) * 2;
    bf16* w_dnT   = (bf16*)p;  p += (size_t)E_ * MI_ * H_ * 2;
    bf16* w_sgT   = (bf16*)p;  p += (size_t)H_ * SI_ * 2;
    bf16* w_suT   = (bf16*)p;  p += (size_t)H_ * SI_ * 2;
    bf16* w_sdT   = (bf16*)p;  p += (size_t)SI_ * H_ * 2;
    bf16* hiddenE = (bf16*)p;  p += (size_t)TK_ * MI_ * 2;
    bf16* sh_hid  = (bf16*)p;  p += (size_t)T_ * SI_ * 2;
    bf16* eo      = (bf16*)p;  p += (size_t)TK_ * H_ * 2;
    float* gate_s = (float*)p; p += (size_t)T_ * 4;
    int*  top_i   = (int*)p;   p += (size_t)T_ * 2 * 4;
    float* top_w  = (float*)p; p += (size_t)T_ * 2 * 4;
    int*  slot_pos= (int*)p;   p += (size_t)T_ * 2 * 4;
    int*  slot_tok= (int*)p;   p += (size_t)TK_ * 4;
    int*  offsets = (int*)p;   p += 17 * 4;

    // conversions + transposes
    k_convert<<<dim3(T_*H_/4/256), 256, 0, stream>>>(x, xb, T_*H_/4);
    k_transpose<<<dim3(32, 32, 16), dim3(32, 8), 0, stream>>>(wgu, w_guT, 1024, 1024);
    k_transpose<<<dim3(32, 16, 16), dim3(32, 8), 0, stream>>>(wdn, w_dnT, 512, 1024);
    k_transpose<<<dim3(64, 32, 1),  dim3(32, 8), 0, stream>>>(wsg, w_sgT, 1024, 2048);
    k_transpose<<<dim3(64, 32, 1),  dim3(32, 8), 0, stream>>>(wsu, w_suT, 1024, 2048);
    k_transpose<<<dim3(32, 64, 1),  dim3(32, 8), 0, stream>>>(wsd, w_sdT, 2048, 1024);

    // routing (atomic-free)
    k_router<<<dim3(T_/4), 256, 0, stream>>>(x, rw, segw, logits, top_i, top_w, gate_s);
    k_count<<<dim3(1), 256, 0, stream>>>(top_i, offsets);
    k_fillscan<<<dim3(E_), 256, 0, stream>>>(top_i, offsets, slot_tok, slot_pos);

    // expert path
    k_gemm<0,1024><<<dim3(MI_/64, 32, E_), 256, 0, stream>>>(xb, w_guT, nullptr, slot_tok, offsets, nullptr, hiddenE, nullptr);
    k_gemm<2, 512><<<dim3(H_/128, 32, E_), 256, 0, stream>>>(hiddenE, w_dnT, nullptr, nullptr, offsets, nullptr, eo, nullptr);

    // shared expert path
    k_gemm<1,1024><<<dim3(SI_/64, 32, 1), 256, 0, stream>>>(xb, w_sgT, w_suT, nullptr, offsets, nullptr, sh_hid, nullptr);
    k_gemm<3,2048><<<dim3(H_/128, 32, 1), 256, 0, stream>>>(sh_hid, w_sdT, nullptr, nullptr, offsets, gate_s, nullptr, out);

    // combine expert contributions into d_out
    k_combine<<<dim3(T_*256/256), 256, 0, stream>>>(out, eo, slot_pos, top_w);
}

// Round 5
// 436.143 us; speedup vs baseline: 1.0109x; 1.0109x over previous
//
#include <hip/hip_runtime.h>
#include <hip/hip_bf16.h>
#include <cstdint>

#define T_  4096
#define H_  1024
#define E_  16
#define MI_ 512
#define SI_ 2048
#define TK_ 8192   // T_ * K(=2)

typedef __bf16 bf16;
typedef bf16  bf16x8 __attribute__((ext_vector_type(8)));
typedef bf16  bf16x4 __attribute__((ext_vector_type(4)));
typedef float f32x4  __attribute__((ext_vector_type(4)));

// async global->LDS, 16B per lane. LDS dest = wave-uniform base + lane*16.
__device__ __forceinline__ void gload16(const bf16* g, bf16* lds) {
    __builtin_amdgcn_global_load_lds(
        (const __attribute__((address_space(1))) void*)(uintptr_t)(const void*)g,
        (__attribute__((address_space(3))) void*)(uintptr_t)(void*)lds,
        16, 0, 0);
}

// ---------------- fp32 -> bf16 flat convert (vectorized) ----------------
__global__ void k_convert(const float* __restrict__ src, bf16* __restrict__ dst, int n4) {
    int i = blockIdx.x * blockDim.x + threadIdx.x;
    if (i < n4) {
        float4 v = reinterpret_cast<const float4*>(src)[i];
        bf16x4 o;
        o[0] = (bf16)v.x; o[1] = (bf16)v.y; o[2] = (bf16)v.z; o[3] = (bf16)v.w;
        reinterpret_cast<bf16x4*>(dst)[i] = o;
    }
}

// ---------------- fp32 [R][C] -> bf16 [C][R] transpose (per z-slice) ----------------
__global__ void k_transpose(const float* __restrict__ src, bf16* __restrict__ dst, int R, int C) {
    __shared__ float tile[32][33];
    size_t zoff = (size_t)blockIdx.z * (size_t)R * (size_t)C;
    src += zoff; dst += zoff;
    int c  = blockIdx.x * 32 + threadIdx.x;
    #pragma unroll
    for (int i = 0; i < 4; i++) {
        int r = blockIdx.y * 32 + threadIdx.y + i * 8;
        tile[threadIdx.y + i * 8][threadIdx.x] = src[(size_t)r * C + c];
    }
    __syncthreads();
    int rr = blockIdx.y * 32 + threadIdx.x;   // original row -> new col
    #pragma unroll
    for (int i = 0; i < 4; i++) {
        int cc = blockIdx.x * 32 + threadIdx.y + i * 8;  // original col -> new row
        dst[(size_t)cc * R + rr] = (bf16)tile[threadIdx.x][threadIdx.y + i * 8];
    }
}

// ---------------- router: logits (fp32), top-2, shared gate scalar. NO atomics. ----------------
__global__ __launch_bounds__(256) void k_router(
    const float* __restrict__ x, const float* __restrict__ rw,
    const float* __restrict__ segw, float* __restrict__ logits_out,
    int* __restrict__ top_i, float* __restrict__ top_w,
    float* __restrict__ gate_scalar)
{
    int wid = threadIdx.x >> 6, lane = threadIdx.x & 63;
    int t = blockIdx.x * 4 + wid;
    const float* xr = x + (size_t)t * H_;
    float acc[E_];
    #pragma unroll
    for (int e = 0; e < E_; e++) acc[e] = 0.f;
    float accg = 0.f;
    for (int j = 0; j < H_ / 64; j++) {
        int h = j * 64 + lane;
        float xv = xr[h];
        const float4* wrow = reinterpret_cast<const float4*>(rw + (size_t)h * E_);
        #pragma unroll
        for (int q = 0; q < 4; q++) {
            float4 w4 = wrow[q];
            acc[q*4+0] += xv * w4.x; acc[q*4+1] += xv * w4.y;
            acc[q*4+2] += xv * w4.z; acc[q*4+3] += xv * w4.w;
        }
        accg += xv * segw[h];
    }
    #pragma unroll
    for (int off = 32; off >= 1; off >>= 1) {
        #pragma unroll
        for (int e = 0; e < E_; e++) acc[e] += __shfl_xor(acc[e], off);
        accg += __shfl_xor(accg, off);
    }
    if (lane == 0) {
        float* lo = logits_out + (size_t)t * E_;
        #pragma unroll
        for (int e = 0; e < E_; e++) lo[e] = acc[e];
        int i0 = 0; float l0 = acc[0];
        #pragma unroll
        for (int e = 1; e < E_; e++) if (acc[e] > l0) { l0 = acc[e]; i0 = e; }
        int i1 = -1; float l1 = -1e30f;
        #pragma unroll
        for (int e = 0; e < E_; e++) if (e != i0 && acc[e] > l1) { l1 = acc[e]; i1 = e; }
        float w0 = 1.f / (1.f + expf(l1 - l0));   // p0/(p0+p1)
        top_i[t*2] = i0; top_i[t*2+1] = i1;
        top_w[t*2] = w0; top_w[t*2+1] = 1.f - w0;
        gate_scalar[t] = 1.f / (1.f + expf(-accg));
    }
}

// ---------------- counts + offsets from top_i, single block, no global atomics ----------------
__global__ __launch_bounds__(256) void k_count(const int* __restrict__ top_i, int* __restrict__ offsets) {
    __shared__ int hist[256][17];
    int tid = threadIdx.x;
    #pragma unroll
    for (int e = 0; e < E_; e++) hist[tid][e] = 0;
    __syncthreads();
    const int* mine = top_i + tid * 32;
    #pragma unroll
    for (int j = 0; j < 32; j++) hist[tid][mine[j]]++;
    __syncthreads();
    if (tid < E_) {
        int s = 0;
        for (int r = 0; r < 256; r++) s += hist[r][tid];
        hist[0][tid] = s;
    }
    __syncthreads();
    if (tid == 0) {
        int s = 0;
        for (int e = 0; e < E_; e++) { offsets[e] = s; s += hist[0][e]; }
        offsets[E_] = s;
    }
}

// ---------------- deterministic slot assignment by rank (prefix scan), one block per expert ----------------
__global__ __launch_bounds__(256) void k_fillscan(
    const int* __restrict__ top_i, const int* __restrict__ offsets,
    int* __restrict__ slot_token, int* __restrict__ slot_pos)
{
    int e = blockIdx.x;
    int tid = threadIdx.x;
    int lane = tid & 63, w = tid >> 6;
    __shared__ int wsum[4];

    int t0 = tid * 16;
    unsigned f0 = 0, f1 = 0;
    int c = 0;
    #pragma unroll
    for (int j = 0; j < 16; j++) {
        int t = t0 + j;
        int a = top_i[t*2], b = top_i[t*2+1];
        if (a == e)      { f0 |= 1u << j; c++; }
        else if (b == e) { f1 |= 1u << j; c++; }
    }
    int incl = c;
    #pragma unroll
    for (int off = 1; off < 64; off <<= 1) {
        int v = __shfl_up(incl, off);
        if (lane >= off) incl += v;
    }
    if (lane == 63) wsum[w] = incl;
    __syncthreads();
    int wbase = 0;
    for (int i = 0; i < w; i++) wbase += wsum[i];
    int pos = offsets[e] + wbase + (incl - c);
    #pragma unroll
    for (int j = 0; j < 16; j++) {
        int t = t0 + j;
        if ((f0 >> j) & 1u)      { slot_token[pos] = t; slot_pos[t*2]   = pos; pos++; }
        else if ((f1 >> j) & 1u) { slot_token[pos] = t; slot_pos[t*2+1] = pos; pos++; }
    }
}

// ---------------- unified GEMM: dbuf prefetch, compiler barriers ----------------
// MODE 0: expert gate/up + silu-mul -> hiddenE (bf16), A = xb gathered via slot_token, K=1024
// MODE 1: shared gate/up + silu-mul -> sh_hid (bf16), K=1024
// MODE 2: expert down -> eo (bf16), A = hiddenE (slot rows), K=512
// MODE 3: shared down + sigmoid-gate + expert-combine -> d_out (f32), K=2048
// Tile: 128 rows x (GU: 64 paired cols / DOWN: 128 cols), BK=32, 256 threads.
template<int MODE, int KDIM>
__global__ __launch_bounds__(256) void k_gemm(
    const bf16* __restrict__ A, const bf16* __restrict__ Bbase, const bf16* __restrict__ Bbase2,
    const int* __restrict__ slot_token, const int* __restrict__ offsets,
    const float* __restrict__ gate_s,
    const bf16* __restrict__ eo_in, const int* __restrict__ slot_pos, const float* __restrict__ top_w,
    bf16* __restrict__ out_bf, float* __restrict__ out_f32)
{
    constexpr bool EXPERT = (MODE == 0 || MODE == 2);
    constexpr bool GU     = (MODE <= 1);
    int e = blockIdx.z;
    int base = EXPERT ? offsets[e] : 0;
    int cnt  = EXPERT ? offsets[e+1] - base : T_;

    // bijective XCD swizzle over the (x,y) plane (plane size is a multiple of 8)
    int nwg = gridDim.x * gridDim.y;
    int p   = blockIdx.y * gridDim.x + blockIdx.x;
    int swz = (p & 7) * (nwg >> 3) + (p >> 3);
    int nt = swz % gridDim.x, mt = swz / gridDim.x;
    if (mt * 128 >= cnt) return;

    const bf16 *B0, *B1;
    if (MODE == 0) {
        const bf16* wb = Bbase + (size_t)e * (2 * MI_) * H_;
        B0 = wb + (size_t)(nt * 64) * KDIM;
        B1 = wb + (size_t)(MI_ + nt * 64) * KDIM;
    } else if (MODE == 1) {
        B0 = Bbase  + (size_t)(nt * 64) * KDIM;
        B1 = Bbase2 + (size_t)(nt * 64) * KDIM;
    } else if (MODE == 2) {
        const bf16* wb = Bbase + (size_t)e * H_ * MI_;
        B0 = wb + (size_t)(nt * 128) * KDIM;
        B1 = B0 + (size_t)64 * KDIM;
    } else {
        B0 = Bbase + (size_t)(nt * 128) * KDIM;
        B1 = B0 + (size_t)64 * KDIM;
    }

    __shared__ __align__(16) bf16 As[2][128 * 32];
    __shared__ __align__(16) bf16 Bs[2][128 * 32];

    int tid = threadIdx.x, w = tid >> 6, l = tid & 63;
    int srow = l >> 2;            // 0..15
    int scol = (l & 3) * 8;       // bf16 elems (16B chunks)

    // per-lane global source pointers (fixed across k-loop)
    const bf16* asrc[2];
    const bf16* bsrc[2];
    #pragma unroll
    for (int i = 0; i < 2; i++) {
        int r = i * 64 + w * 16 + srow;         // row within 128-tile
        if (MODE == 0) {
            int s = mt * 128 + r; if (s >= cnt) s = cnt - 1;
            asrc[i] = A + (size_t)slot_token[base + s] * KDIM + scol;
        } else if (MODE == 2) {
            int s = mt * 128 + r; if (s >= cnt) s = cnt - 1;
            asrc[i] = A + (size_t)(base + s) * KDIM + scol;
        } else {
            asrc[i] = A + (size_t)(mt * 128 + r) * KDIM + scol;
        }
        bsrc[i] = (r < 64 ? B0 + (size_t)r * KDIM : B1 + (size_t)(r - 64) * KDIM) + scol;
    }
    // wave-uniform LDS staging offsets (HW adds lane*16B)
    int a_off0 = (0  + w * 16) * 32;
    int a_off1 = (64 + w * 16) * 32;

    int lr = l & 15, kq = l >> 4;
    f32x4 acc[2][8];
    #pragma unroll
    for (int mi = 0; mi < 2; mi++)
        #pragma unroll
        for (int ni = 0; ni < 8; ni++) acc[mi][ni] = (f32x4){0.f, 0.f, 0.f, 0.f};

    auto STAGE = [&](int b, int k0) {
        gload16(asrc[0] + k0, &As[b][a_off0]);
        gload16(asrc[1] + k0, &As[b][a_off1]);
        gload16(bsrc[0] + k0, &Bs[b][a_off0]);
        gload16(bsrc[1] + k0, &Bs[b][a_off1]);
    };
    auto COMPUTE = [&](int b) {
        bf16x8 af[2], bfr[8];
        #pragma unroll
        for (int mi = 0; mi < 2; mi++)
            af[mi] = *reinterpret_cast<const bf16x8*>(&As[b][(w * 32 + mi * 16 + lr) * 32 + kq * 8]);
        #pragma unroll
        for (int ni = 0; ni < 8; ni++)
            bfr[ni] = *reinterpret_cast<const bf16x8*>(&Bs[b][(ni * 16 + lr) * 32 + kq * 8]);
        #pragma unroll
        for (int mi = 0; mi < 2; mi++)
            #pragma unroll
            for (int ni = 0; ni < 8; ni++)
                acc[mi][ni] = __builtin_amdgcn_mfma_f32_16x16x32_bf16(af[mi], bfr[ni], acc[mi][ni], 0, 0, 0);
    };

    // prologue: stage tile 0; __syncthreads drains vmcnt + barriers (compiler-managed)
    STAGE(0, 0);
    __syncthreads();

    int cur = 0;
    for (int k0 = 32; k0 < KDIM; k0 += 32) {
        STAGE(cur ^ 1, k0);      // prefetch next K-tile; flies during COMPUTE
        COMPUTE(cur);
        __syncthreads();         // drain prefetch + protect buffer reuse
        cur ^= 1;
    }
    COMPUTE(cur);

    // epilogue: D row = A_row_base + kq*4 + r, col = B_row_base + lr (m89-verified)
    #pragma unroll
    for (int mi = 0; mi < 2; mi++)
        #pragma unroll
        for (int ni = 0; ni < (GU ? 4 : 8); ni++)
            #pragma unroll
            for (int r = 0; r < 4; r++) {
                int row = mt * 128 + w * 32 + mi * 16 + kq * 4 + r;
                if (row < cnt) {
                    if (GU) {
                        constexpr int NOUT = (MODE == 0) ? MI_ : SI_;
                        int col = nt * 64 + ni * 16 + lr;
                        float g = acc[mi][ni][r], u = acc[mi][ni + 4][r];
                        float hv = u * (g / (1.f + expf(-g)));
                        out_bf[(size_t)(base + row) * NOUT + col] = (bf16)hv;
                    } else if (MODE == 2) {
                        int col = nt * 128 + ni * 16 + lr;
                        out_bf[(size_t)(base + row) * H_ + col] = (bf16)acc[mi][ni][r];
                    } else {
                        int col = nt * 128 + ni * 16 + lr;
                        int s0 = slot_pos[row*2], s1 = slot_pos[row*2+1];
                        float w0 = top_w[row*2],  w1 = top_w[row*2+1];
                        float e0 = (float)eo_in[(size_t)s0 * H_ + col];
                        float e1 = (float)eo_in[(size_t)s1 * H_ + col];
                        out_f32[(size_t)row * H_ + col] =
                            gate_s[row] * acc[mi][ni][r] + w0 * e0 + w1 * e1;
                    }
                }
            }
}

extern "C" void kernel_launch(void* const* d_in, const int* in_sizes, int n_in,
                              void* d_out, int out_size, void* d_ws, size_t ws_size,
                              hipStream_t stream) {
    const float* x    = (const float*)d_in[0];
    const float* rw   = (const float*)d_in[1];
    const float* wgu  = (const float*)d_in[2];
    const float* wdn  = (const float*)d_in[3];
    const float* wsg  = (const float*)d_in[4];
    const float* wsu  = (const float*)d_in[5];
    const float* wsd  = (const float*)d_in[6];
    const float* segw = (const float*)d_in[7];
    float* out    = (float*)d_out;
    float* logits = (float*)d_out + (size_t)T_ * H_;

    char* p = (char*)d_ws;
    bf16* xb      = (bf16*)p;  p += (size_t)T_ * H_ * 2;
    bf16* w_guT   = (bf16*)p;  p += (size_t)E_ * H_ * (2*MI_) * 2;
    bf16* w_dnT   = (bf16*)p;  p += (size_t)E_ * MI_ * H_ * 2;
    bf16* w_sgT   = (bf16*)p;  p += (size_t)H_ * SI_ * 2;
    bf16* w_suT   = (bf16*)p;  p += (size_t)H_ * SI_ * 2;
    bf16* w_sdT   = (bf16*)p;  p += (size_t)SI_ * H_ * 2;
    bf16* hiddenE = (bf16*)p;  p += (size_t)TK_ * MI_ * 2;
    bf16* sh_hid  = (bf16*)p;  p += (size_t)T_ * SI_ * 2;
    bf16* eo      = (bf16*)p;  p += (size_t)TK_ * H_ * 2;
    float* gate_s = (float*)p; p += (size_t)T_ * 4;
    int*  top_i   = (int*)p;   p += (size_t)T_ * 2 * 4;
    float* top_w  = (float*)p; p += (size_t)T_ * 2 * 4;
    int*  slot_pos= (int*)p;   p += (size_t)T_ * 2 * 4;
    int*  slot_tok= (int*)p;   p += (size_t)TK_ * 4;
    int*  offsets = (int*)p;   p += 17 * 4;

    // conversions + transposes
    k_convert<<<dim3(T_*H_/4/256), 256, 0, stream>>>(x, xb, T_*H_/4);
    k_transpose<<<dim3(32, 32, 16), dim3(32, 8), 0, stream>>>(wgu, w_guT, 1024, 1024);
    k_transpose<<<dim3(32, 16, 16), dim3(32, 8), 0, stream>>>(wdn, w_dnT, 512, 1024);
    k_transpose<<<dim3(64, 32, 1),  dim3(32, 8), 0, stream>>>(wsg, w_sgT, 1024, 2048);
    k_transpose<<<dim3(64, 32, 1),  dim3(32, 8), 0, stream>>>(wsu, w_suT, 1024, 2048);
    k_transpose<<<dim3(32, 64, 1),  dim3(32, 8), 0, stream>>>(wsd, w_sdT, 2048, 1024);

    // routing (atomic-free)
    k_router<<<dim3(T_/4), 256, 0, stream>>>(x, rw, segw, logits, top_i, top_w, gate_s);
    k_count<<<dim3(1), 256, 0, stream>>>(top_i, offsets);
    k_fillscan<<<dim3(E_), 256, 0, stream>>>(top_i, offsets, slot_tok, slot_pos);

    // expert path
    k_gemm<0,1024><<<dim3(MI_/64, 32, E_), 256, 0, stream>>>(xb, w_guT, nullptr, slot_tok, offsets, nullptr, nullptr, nullptr, nullptr, hiddenE, nullptr);
    k_gemm<2, 512><<<dim3(H_/128, 32, E_), 256, 0, stream>>>(hiddenE, w_dnT, nullptr, nullptr, offsets, nullptr, nullptr, nullptr, nullptr, eo, nullptr);

    // shared expert path (MODE 3 fuses sigmoid gate + expert combine into the epilogue)
    k_gemm<1,1024><<<dim3(SI_/64, 32, 1), 256, 0, stream>>>(xb, w_sgT, w_suT, nullptr, offsets, nullptr, nullptr, nullptr, nullptr, sh_hid, nullptr);
    k_gemm<3,2048><<<dim3(H_/128, 32, 1), 256, 0, stream>>>(sh_hid, w_sdT, nullptr, nullptr, offsets, gate_s, eo, slot_pos, top_w, nullptr, out);
}

// Round 6
// 239.882 us; speedup vs baseline: 1.8380x; 1.8182x over previous
//
#include <hip/hip_runtime.h>
#include <hip/hip_bf16.h>
#include <cstdint>

#define T_  4096
#define H_  1024
#define E_  16
#define MI_ 512
#define SI_ 2048
#define TK_ 8192   // T_ * K(=2)

typedef __bf16 bf16;
typedef bf16  bf16x8 __attribute__((ext_vector_type(8)));
typedef bf16  bf16x4 __attribute__((ext_vector_type(4)));
typedef float f32x4  __attribute__((ext_vector_type(4)));

// async global->LDS, 16B per lane. LDS dest = wave-uniform base + lane*16.
__device__ __forceinline__ void gload16(const bf16* g, bf16* lds) {
    __builtin_amdgcn_global_load_lds(
        (const __attribute__((address_space(1))) void*)(uintptr_t)(const void*)g,
        (__attribute__((address_space(3))) void*)(uintptr_t)(void*)lds,
        16, 0, 0);
}

// ---------------- fp32 -> bf16 flat convert (vectorized) ----------------
__global__ void k_convert(const float* __restrict__ src, bf16* __restrict__ dst, int n4) {
    int i = blockIdx.x * blockDim.x + threadIdx.x;
    if (i < n4) {
        float4 v = reinterpret_cast<const float4*>(src)[i];
        bf16x4 o;
        o[0] = (bf16)v.x; o[1] = (bf16)v.y; o[2] = (bf16)v.z; o[3] = (bf16)v.w;
        reinterpret_cast<bf16x4*>(dst)[i] = o;
    }
}

// ---------------- fp32 [R][C] -> bf16 [C][R] transpose (per z-slice) ----------------
__global__ void k_transpose(const float* __restrict__ src, bf16* __restrict__ dst, int R, int C) {
    __shared__ float tile[32][33];
    size_t zoff = (size_t)blockIdx.z * (size_t)R * (size_t)C;
    src += zoff; dst += zoff;
    int c  = blockIdx.x * 32 + threadIdx.x;
    #pragma unroll
    for (int i = 0; i < 4; i++) {
        int r = blockIdx.y * 32 + threadIdx.y + i * 8;
        tile[threadIdx.y + i * 8][threadIdx.x] = src[(size_t)r * C + c];
    }
    __syncthreads();
    int rr = blockIdx.y * 32 + threadIdx.x;   // original row -> new col
    #pragma unroll
    for (int i = 0; i < 4; i++) {
        int cc = blockIdx.x * 32 + threadIdx.y + i * 8;  // original col -> new row
        dst[(size_t)cc * R + rr] = (bf16)tile[threadIdx.x][threadIdx.y + i * 8];
    }
}

// ---------------- router: logits (fp32), top-2, shared gate scalar. NO atomics. ----------------
__global__ __launch_bounds__(256) void k_router(
    const float* __restrict__ x, const float* __restrict__ rw,
    const float* __restrict__ segw, float* __restrict__ logits_out,
    int* __restrict__ top_i, float* __restrict__ top_w,
    float* __restrict__ gate_scalar)
{
    int wid = threadIdx.x >> 6, lane = threadIdx.x & 63;
    int t = blockIdx.x * 4 + wid;
    const float* xr = x + (size_t)t * H_;
    float acc[E_];
    #pragma unroll
    for (int e = 0; e < E_; e++) acc[e] = 0.f;
    float accg = 0.f;
    for (int j = 0; j < H_ / 64; j++) {
        int h = j * 64 + lane;
        float xv = xr[h];
        const float4* wrow = reinterpret_cast<const float4*>(rw + (size_t)h * E_);
        #pragma unroll
        for (int q = 0; q < 4; q++) {
            float4 w4 = wrow[q];
            acc[q*4+0] += xv * w4.x; acc[q*4+1] += xv * w4.y;
            acc[q*4+2] += xv * w4.z; acc[q*4+3] += xv * w4.w;
        }
        accg += xv * segw[h];
    }
    #pragma unroll
    for (int off = 32; off >= 1; off >>= 1) {
        #pragma unroll
        for (int e = 0; e < E_; e++) acc[e] += __shfl_xor(acc[e], off);
        accg += __shfl_xor(accg, off);
    }
    if (lane == 0) {
        float* lo = logits_out + (size_t)t * E_;
        #pragma unroll
        for (int e = 0; e < E_; e++) lo[e] = acc[e];
        int i0 = 0; float l0 = acc[0];
        #pragma unroll
        for (int e = 1; e < E_; e++) if (acc[e] > l0) { l0 = acc[e]; i0 = e; }
        int i1 = -1; float l1 = -1e30f;
        #pragma unroll
        for (int e = 0; e < E_; e++) if (e != i0 && acc[e] > l1) { l1 = acc[e]; i1 = e; }
        float w0 = 1.f / (1.f + expf(l1 - l0));   // p0/(p0+p1)
        top_i[t*2] = i0; top_i[t*2+1] = i1;
        top_w[t*2] = w0; top_w[t*2+1] = 1.f - w0;
        gate_scalar[t] = 1.f / (1.f + expf(-accg));
    }
}

// ---------------- counts + offsets from top_i, single block, no global atomics ----------------
__global__ __launch_bounds__(256) void k_count(const int* __restrict__ top_i, int* __restrict__ offsets) {
    __shared__ int hist[256][17];
    int tid = threadIdx.x;
    #pragma unroll
    for (int e = 0; e < E_; e++) hist[tid][e] = 0;
    __syncthreads();
    const int* mine = top_i + tid * 32;
    #pragma unroll
    for (int j = 0; j < 32; j++) hist[tid][mine[j]]++;
    __syncthreads();
    if (tid < E_) {
        int s = 0;
        for (int r = 0; r < 256; r++) s += hist[r][tid];
        hist[0][tid] = s;
    }
    __syncthreads();
    if (tid == 0) {
        int s = 0;
        for (int e = 0; e < E_; e++) { offsets[e] = s; s += hist[0][e]; }
        offsets[E_] = s;
    }
}

// ---------------- deterministic slot assignment by rank (prefix scan), one block per expert ----------------
__global__ __launch_bounds__(256) void k_fillscan(
    const int* __restrict__ top_i, const int* __restrict__ offsets,
    int* __restrict__ slot_token, int* __restrict__ slot_pos)
{
    int e = blockIdx.x;
    int tid = threadIdx.x;
    int lane = tid & 63, w = tid >> 6;
    __shared__ int wsum[4];

    int t0 = tid * 16;
    unsigned f0 = 0, f1 = 0;
    int c = 0;
    #pragma unroll
    for (int j = 0; j < 16; j++) {
        int t = t0 + j;
        int a = top_i[t*2], b = top_i[t*2+1];
        if (a == e)      { f0 |= 1u << j; c++; }
        else if (b == e) { f1 |= 1u << j; c++; }
    }
    int incl = c;
    #pragma unroll
    for (int off = 1; off < 64; off <<= 1) {
        int v = __shfl_up(incl, off);
        if (lane >= off) incl += v;
    }
    if (lane == 63) wsum[w] = incl;
    __syncthreads();
    int wbase = 0;
    for (int i = 0; i < w; i++) wbase += wsum[i];
    int pos = offsets[e] + wbase + (incl - c);
    #pragma unroll
    for (int j = 0; j < 16; j++) {
        int t = t0 + j;
        if ((f0 >> j) & 1u)      { slot_token[pos] = t; slot_pos[t*2]   = pos; pos++; }
        else if ((f1 >> j) & 1u) { slot_token[pos] = t; slot_pos[t*2+1] = pos; pos++; }
    }
}

// ======= Phase A: expert gate/up (bid<4096) + shared gate/up (bid>=4096), K=1024, BK=64 =======
// R3-proven loop shape (stage -> drain -> barrier -> compute), single buffer.
// LDS XOR chunk-swizzle: linear gload dest, inverse-swizzled global src, swizzled ds_read.
__global__ __launch_bounds__(256) void k_mlp1(
    const bf16* __restrict__ xb, const bf16* __restrict__ wgu,
    const bf16* __restrict__ wsg, const bf16* __restrict__ wsu,
    const int* __restrict__ slot_token, const int* __restrict__ offsets,
    bf16* __restrict__ hiddenE, bf16* __restrict__ sh_hid)
{
    int bid = blockIdx.x;
    bool expert = bid < 4096;
    int nt, mt, base, cnt;
    const bf16 *B0, *B1;
    bf16* outp; int nout;
    if (expert) {
        int e = bid >> 8; int r = bid & 255; nt = r & 7; mt = r >> 3;
        base = offsets[e]; cnt = offsets[e+1] - base;
        if (mt * 128 >= cnt) return;
        const bf16* wb = wgu + (size_t)e * (2 * MI_) * H_;
        B0 = wb + (size_t)(nt * 64) * H_;
        B1 = wb + (size_t)(MI_ + nt * 64) * H_;
        outp = hiddenE; nout = MI_;
    } else {
        int r = bid - 4096; nt = r & 31; mt = r >> 5;
        base = 0; cnt = T_;
        B0 = wsg + (size_t)(nt * 64) * H_;
        B1 = wsu + (size_t)(nt * 64) * H_;
        outp = sh_hid; nout = SI_;
    }

    __shared__ __align__(16) bf16 As[128 * 64];
    __shared__ __align__(16) bf16 Bs[128 * 64];

    int tid = threadIdx.x, w = tid >> 6, l = tid & 63;
    int lrow8 = l >> 3;                       // 0..7: row within 8-row group
    int col_off = ((l & 7) ^ lrow8) * 8;      // inverse-swizzled global chunk

    const bf16* asrc[4];
    const bf16* bsrc[4];
    #pragma unroll
    for (int g = 0; g < 4; g++) {
        int rt = g * 32 + w * 8 + lrow8;      // row within 128-tile
        int s = mt * 128 + rt; if (s >= cnt) s = cnt - 1;
        const bf16* arow = expert ? xb + (size_t)slot_token[base + s] * H_
                                  : xb + (size_t)s * H_;
        asrc[g] = arow + col_off;
        bsrc[g] = (rt < 64 ? B0 + (size_t)rt * H_ : B1 + (size_t)(rt - 64) * H_) + col_off;
    }

    int lr = l & 15, kq = l >> 4;
    f32x4 acc[2][8];
    #pragma unroll
    for (int mi = 0; mi < 2; mi++)
        #pragma unroll
        for (int ni = 0; ni < 8; ni++) acc[mi][ni] = (f32x4){0.f, 0.f, 0.f, 0.f};

    for (int k0 = 0; k0 < H_; k0 += 64) {
        __syncthreads();                      // protect LDS reuse
        #pragma unroll
        for (int g = 0; g < 4; g++) {
            gload16(asrc[g] + k0, &As[(g * 32 + w * 8) * 64]);
            gload16(bsrc[g] + k0, &Bs[(g * 32 + w * 8) * 64]);
        }
        asm volatile("s_waitcnt vmcnt(0)" ::: "memory");
        __syncthreads();
        #pragma unroll
        for (int ks = 0; ks < 2; ks++) {
            int cl = ((ks * 4 + kq) ^ (lr & 7)) * 8;   // swizzled read chunk
            bf16x8 af[2], bfr[8];
            #pragma unroll
            for (int mi = 0; mi < 2; mi++)
                af[mi] = *reinterpret_cast<const bf16x8*>(&As[(w * 32 + mi * 16 + lr) * 64 + cl]);
            #pragma unroll
            for (int ni = 0; ni < 8; ni++)
                bfr[ni] = *reinterpret_cast<const bf16x8*>(&Bs[(ni * 16 + lr) * 64 + cl]);
            #pragma unroll
            for (int mi = 0; mi < 2; mi++)
                #pragma unroll
                for (int ni = 0; ni < 8; ni++)
                    acc[mi][ni] = __builtin_amdgcn_mfma_f32_16x16x32_bf16(af[mi], bfr[ni], acc[mi][ni], 0, 0, 0);
        }
    }

    // epilogue: row = base + kq*4 + r, col = Brow-base + lr; gate=ni, up=ni+4 share col
    #pragma unroll
    for (int mi = 0; mi < 2; mi++)
        #pragma unroll
        for (int ni = 0; ni < 4; ni++)
            #pragma unroll
            for (int r = 0; r < 4; r++) {
                int row = mt * 128 + w * 32 + mi * 16 + kq * 4 + r;
                if (row < cnt) {
                    int col = nt * 64 + ni * 16 + lr;
                    float g = acc[mi][ni][r], u = acc[mi][ni + 4][r];
                    float hv = u * (g / (1.f + expf(-g)));
                    outp[(size_t)(base + row) * nout + col] = (bf16)hv;
                }
            }
}

// ======= Phase B: expert down (bid<4096, K=512) + shared down (bid>=4096, K=2048), BK=64 =======
__global__ __launch_bounds__(256) void k_mlp2(
    const bf16* __restrict__ hiddenE, const bf16* __restrict__ sh_hid,
    const bf16* __restrict__ wdn, const bf16* __restrict__ wsd,
    const int* __restrict__ offsets, const float* __restrict__ gate_s,
    bf16* __restrict__ eo, float* __restrict__ out)
{
    int bid = blockIdx.x;
    bool expert = bid < 4096;
    int nt, mt, base, cnt, KD;
    const bf16 *Ab, *B0;
    if (expert) {
        int e = bid >> 8; int r = bid & 255; nt = r & 7; mt = r >> 3;
        base = offsets[e]; cnt = offsets[e+1] - base;
        if (mt * 128 >= cnt) return;
        KD = MI_;
        Ab = hiddenE;
        B0 = wdn + (size_t)e * H_ * MI_ + (size_t)(nt * 128) * MI_;
    } else {
        int r = bid - 4096; nt = r & 7; mt = r >> 3;
        base = 0; cnt = T_; KD = SI_;
        Ab = sh_hid;
        B0 = wsd + (size_t)(nt * 128) * SI_;
    }

    __shared__ __align__(16) bf16 As[128 * 64];
    __shared__ __align__(16) bf16 Bs[128 * 64];

    int tid = threadIdx.x, w = tid >> 6, l = tid & 63;
    int lrow8 = l >> 3;
    int col_off = ((l & 7) ^ lrow8) * 8;

    const bf16* asrc[4];
    const bf16* bsrc[4];
    #pragma unroll
    for (int g = 0; g < 4; g++) {
        int rt = g * 32 + w * 8 + lrow8;
        int s = mt * 128 + rt; if (s >= cnt) s = cnt - 1;
        asrc[g] = Ab + (size_t)(base + s) * KD + col_off;
        bsrc[g] = B0 + (size_t)rt * KD + col_off;
    }

    int lr = l & 15, kq = l >> 4;
    f32x4 acc[2][8];
    #pragma unroll
    for (int mi = 0; mi < 2; mi++)
        #pragma unroll
        for (int ni = 0; ni < 8; ni++) acc[mi][ni] = (f32x4){0.f, 0.f, 0.f, 0.f};

    for (int k0 = 0; k0 < KD; k0 += 64) {
        __syncthreads();
        #pragma unroll
        for (int g = 0; g < 4; g++) {
            gload16(asrc[g] + k0, &As[(g * 32 + w * 8) * 64]);
            gload16(bsrc[g] + k0, &Bs[(g * 32 + w * 8) * 64]);
        }
        asm volatile("s_waitcnt vmcnt(0)" ::: "memory");
        __syncthreads();
        #pragma unroll
        for (int ks = 0; ks < 2; ks++) {
            int cl = ((ks * 4 + kq) ^ (lr & 7)) * 8;
            bf16x8 af[2], bfr[8];
            #pragma unroll
            for (int mi = 0; mi < 2; mi++)
                af[mi] = *reinterpret_cast<const bf16x8*>(&As[(w * 32 + mi * 16 + lr) * 64 + cl]);
            #pragma unroll
            for (int ni = 0; ni < 8; ni++)
                bfr[ni] = *reinterpret_cast<const bf16x8*>(&Bs[(ni * 16 + lr) * 64 + cl]);
            #pragma unroll
            for (int mi = 0; mi < 2; mi++)
                #pragma unroll
                for (int ni = 0; ni < 8; ni++)
                    acc[mi][ni] = __builtin_amdgcn_mfma_f32_16x16x32_bf16(af[mi], bfr[ni], acc[mi][ni], 0, 0, 0);
        }
    }

    #pragma unroll
    for (int mi = 0; mi < 2; mi++)
        #pragma unroll
        for (int ni = 0; ni < 8; ni++)
            #pragma unroll
            for (int r = 0; r < 4; r++) {
                int row = mt * 128 + w * 32 + mi * 16 + kq * 4 + r;
                if (row < cnt) {
                    int col = nt * 128 + ni * 16 + lr;
                    float v = acc[mi][ni][r];
                    if (expert) eo[(size_t)(base + row) * H_ + col] = (bf16)v;
                    else        out[(size_t)row * H_ + col] = gate_s[row] * v;
                }
            }
}

// ---------------- combine: out += w0*eo[s0] + w1*eo[s1] ----------------
__global__ void k_combine(float* __restrict__ out, const bf16* __restrict__ eo,
                          const int* __restrict__ slot_pos, const float* __restrict__ top_w)
{
    int i = blockIdx.x * blockDim.x + threadIdx.x;
    int t = i >> 8;
    int q = (i & 255) * 4;
    int s0 = slot_pos[t*2], s1 = slot_pos[t*2+1];
    float w0 = top_w[t*2], w1 = top_w[t*2+1];
    bf16x4 e0 = *reinterpret_cast<const bf16x4*>(eo + (size_t)s0 * H_ + q);
    bf16x4 e1 = *reinterpret_cast<const bf16x4*>(eo + (size_t)s1 * H_ + q);
    float4* op = reinterpret_cast<float4*>(out) + i;
    float4 so = *op;
    float4 r;
    r.x = so.x + w0 * (float)e0[0] + w1 * (float)e1[0];
    r.y = so.y + w0 * (float)e0[1] + w1 * (float)e1[1];
    r.z = so.z + w0 * (float)e0[2] + w1 * (float)e1[2];
    r.w = so.w + w0 * (float)e0[3] + w1 * (float)e1[3];
    *op = r;
}

extern "C" void kernel_launch(void* const* d_in, const int* in_sizes, int n_in,
                              void* d_out, int out_size, void* d_ws, size_t ws_size,
                              hipStream_t stream) {
    const float* x    = (const float*)d_in[0];
    const float* rw   = (const float*)d_in[1];
    const float* wgu  = (const float*)d_in[2];
    const float* wdn  = (const float*)d_in[3];
    const float* wsg  = (const float*)d_in[4];
    const float* wsu  = (const float*)d_in[5];
    const float* wsd  = (const float*)d_in[6];
    const float* segw = (const float*)d_in[7];
    float* out    = (float*)d_out;
    float* logits = (float*)d_out + (size_t)T_ * H_;

    char* p = (char*)d_ws;
    bf16* xb      = (bf16*)p;  p += (size_t)T_ * H_ * 2;
    bf16* w_guT   = (bf16*)p;  p += (size_t)E_ * H_ * (2*MI_) * 2;
    bf16* w_dnT   = (bf16*)p;  p += (size_t)E_ * MI_ * H_ * 2;
    bf16* w_sgT   = (bf16*)p;  p += (size_t)H_ * SI_ * 2;
    bf16* w_suT   = (bf16*)p;  p += (size_t)H_ * SI_ * 2;
    bf16* w_sdT   = (bf16*)p;  p += (size_t)SI_ * H_ * 2;
    bf16* hiddenE = (bf16*)p;  p += (size_t)TK_ * MI_ * 2;
    bf16* sh_hid  = (bf16*)p;  p += (size_t)T_ * SI_ * 2;
    bf16* eo      = (bf16*)p;  p += (size_t)TK_ * H_ * 2;
    float* gate_s = (float*)p; p += (size_t)T_ * 4;
    int*  top_i   = (int*)p;   p += (size_t)T_ * 2 * 4;
    float* top_w  = (float*)p; p += (size_t)T_ * 2 * 4;
    int*  slot_pos= (int*)p;   p += (size_t)T_ * 2 * 4;
    int*  slot_tok= (int*)p;   p += (size_t)TK_ * 4;
    int*  offsets = (int*)p;   p += 17 * 4;

    // conversions + transposes
    k_convert<<<dim3(T_*H_/4/256), 256, 0, stream>>>(x, xb, T_*H_/4);
    k_transpose<<<dim3(32, 32, 16), dim3(32, 8), 0, stream>>>(wgu, w_guT, 1024, 1024);
    k_transpose<<<dim3(32, 16, 16), dim3(32, 8), 0, stream>>>(wdn, w_dnT, 512, 1024);
    k_transpose<<<dim3(64, 32, 1),  dim3(32, 8), 0, stream>>>(wsg, w_sgT, 1024, 2048);
    k_transpose<<<dim3(64, 32, 1),  dim3(32, 8), 0, stream>>>(wsu, w_suT, 1024, 2048);
    k_transpose<<<dim3(32, 64, 1),  dim3(32, 8), 0, stream>>>(wsd, w_sdT, 2048, 1024);

    // routing (atomic-free)
    k_router<<<dim3(T_/4), 256, 0, stream>>>(x, rw, segw, logits, top_i, top_w, gate_s);
    k_count<<<dim3(1), 256, 0, stream>>>(top_i, offsets);
    k_fillscan<<<dim3(E_), 256, 0, stream>>>(top_i, offsets, slot_tok, slot_pos);

    // phase A: all gate/up GEMMs in one launch (expert blocks + shared blocks)
    k_mlp1<<<dim3(4096 + 1024), 256, 0, stream>>>(xb, w_guT, w_sgT, w_suT, slot_tok, offsets, hiddenE, sh_hid);
    // phase B: all down GEMMs in one launch
    k_mlp2<<<dim3(4096 + 256), 256, 0, stream>>>(hiddenE, sh_hid, w_dnT, w_sdT, offsets, gate_s, eo, out);

    // combine expert contributions into d_out
    k_combine<<<dim3(T_*256/256), 256, 0, stream>>>(out, eo, slot_pos, top_w);
}

// Round 7
// 220.190 us; speedup vs baseline: 2.0024x; 1.0894x over previous
//
#include <hip/hip_runtime.h>
#include <hip/hip_bf16.h>
#include <cstdint>

#define T_  4096
#define H_  1024
#define E_  16
#define MI_ 512
#define SI_ 2048
#define TK_ 8192   // T_ * K(=2)

typedef __bf16 bf16;
typedef bf16  bf16x8 __attribute__((ext_vector_type(8)));
typedef bf16  bf16x4 __attribute__((ext_vector_type(4)));
typedef float f32x4  __attribute__((ext_vector_type(4)));

// async global->LDS, 16B per lane. LDS dest = wave-uniform base + lane*16.
__device__ __forceinline__ void gload16(const bf16* g, bf16* lds) {
    __builtin_amdgcn_global_load_lds(
        (const __attribute__((address_space(1))) void*)(uintptr_t)(const void*)g,
        (__attribute__((address_space(3))) void*)(uintptr_t)(void*)lds,
        16, 0, 0);
}

// ---------------- fp32 -> bf16 flat convert (vectorized) ----------------
__global__ void k_convert(const float* __restrict__ src, bf16* __restrict__ dst, int n4) {
    int i = blockIdx.x * blockDim.x + threadIdx.x;
    if (i < n4) {
        float4 v = reinterpret_cast<const float4*>(src)[i];
        bf16x4 o;
        o[0] = (bf16)v.x; o[1] = (bf16)v.y; o[2] = (bf16)v.z; o[3] = (bf16)v.w;
        reinterpret_cast<bf16x4*>(dst)[i] = o;
    }
}

// ---------------- fp32 [R][C] -> bf16 [C][R] transpose (per z-slice) ----------------
__global__ void k_transpose(const float* __restrict__ src, bf16* __restrict__ dst, int R, int C) {
    __shared__ float tile[32][33];
    size_t zoff = (size_t)blockIdx.z * (size_t)R * (size_t)C;
    src += zoff; dst += zoff;
    int c  = blockIdx.x * 32 + threadIdx.x;
    #pragma unroll
    for (int i = 0; i < 4; i++) {
        int r = blockIdx.y * 32 + threadIdx.y + i * 8;
        tile[threadIdx.y + i * 8][threadIdx.x] = src[(size_t)r * C + c];
    }
    __syncthreads();
    int rr = blockIdx.y * 32 + threadIdx.x;   // original row -> new col
    #pragma unroll
    for (int i = 0; i < 4; i++) {
        int cc = blockIdx.x * 32 + threadIdx.y + i * 8;  // original col -> new row
        dst[(size_t)cc * R + rr] = (bf16)tile[threadIdx.x][threadIdx.y + i * 8];
    }
}

// ---------------- router: logits (fp32), top-2, shared gate scalar. NO atomics. ----------------
__global__ __launch_bounds__(256) void k_router(
    const float* __restrict__ x, const float* __restrict__ rw,
    const float* __restrict__ segw, float* __restrict__ logits_out,
    int* __restrict__ top_i, float* __restrict__ top_w,
    float* __restrict__ gate_scalar)
{
    int wid = threadIdx.x >> 6, lane = threadIdx.x & 63;
    int t = blockIdx.x * 4 + wid;
    const float* xr = x + (size_t)t * H_;
    float acc[E_];
    #pragma unroll
    for (int e = 0; e < E_; e++) acc[e] = 0.f;
    float accg = 0.f;
    for (int j = 0; j < H_ / 64; j++) {
        int h = j * 64 + lane;
        float xv = xr[h];
        const float4* wrow = reinterpret_cast<const float4*>(rw + (size_t)h * E_);
        #pragma unroll
        for (int q = 0; q < 4; q++) {
            float4 w4 = wrow[q];
            acc[q*4+0] += xv * w4.x; acc[q*4+1] += xv * w4.y;
            acc[q*4+2] += xv * w4.z; acc[q*4+3] += xv * w4.w;
        }
        accg += xv * segw[h];
    }
    #pragma unroll
    for (int off = 32; off >= 1; off >>= 1) {
        #pragma unroll
        for (int e = 0; e < E_; e++) acc[e] += __shfl_xor(acc[e], off);
        accg += __shfl_xor(accg, off);
    }
    if (lane == 0) {
        float* lo = logits_out + (size_t)t * E_;
        #pragma unroll
        for (int e = 0; e < E_; e++) lo[e] = acc[e];
        int i0 = 0; float l0 = acc[0];
        #pragma unroll
        for (int e = 1; e < E_; e++) if (acc[e] > l0) { l0 = acc[e]; i0 = e; }
        int i1 = -1; float l1 = -1e30f;
        #pragma unroll
        for (int e = 0; e < E_; e++) if (e != i0 && acc[e] > l1) { l1 = acc[e]; i1 = e; }
        float w0 = 1.f / (1.f + expf(l1 - l0));   // p0/(p0+p1)
        top_i[t*2] = i0; top_i[t*2+1] = i1;
        top_w[t*2] = w0; top_w[t*2+1] = 1.f - w0;
        gate_scalar[t] = 1.f / (1.f + expf(-accg));
    }
}

// ---------------- counts + offsets from top_i, single block, no global atomics ----------------
__global__ __launch_bounds__(256) void k_count(const int* __restrict__ top_i, int* __restrict__ offsets) {
    __shared__ int hist[256][17];
    int tid = threadIdx.x;
    #pragma unroll
    for (int e = 0; e < E_; e++) hist[tid][e] = 0;
    __syncthreads();
    const int* mine = top_i + tid * 32;
    #pragma unroll
    for (int j = 0; j < 32; j++) hist[tid][mine[j]]++;
    __syncthreads();
    if (tid < E_) {
        int s = 0;
        for (int r = 0; r < 256; r++) s += hist[r][tid];
        hist[0][tid] = s;
    }
    __syncthreads();
    if (tid == 0) {
        int s = 0;
        for (int e = 0; e < E_; e++) { offsets[e] = s; s += hist[0][e]; }
        offsets[E_] = s;
    }
}

// ---------------- deterministic slot assignment by rank (prefix scan), one block per expert ----------------
__global__ __launch_bounds__(256) void k_fillscan(
    const int* __restrict__ top_i, const int* __restrict__ offsets,
    int* __restrict__ slot_token, int* __restrict__ slot_pos)
{
    int e = blockIdx.x;
    int tid = threadIdx.x;
    int lane = tid & 63, w = tid >> 6;
    __shared__ int wsum[4];

    int t0 = tid * 16;
    unsigned f0 = 0, f1 = 0;
    int c = 0;
    #pragma unroll
    for (int j = 0; j < 16; j++) {
        int t = t0 + j;
        int a = top_i[t*2], b = top_i[t*2+1];
        if (a == e)      { f0 |= 1u << j; c++; }
        else if (b == e) { f1 |= 1u << j; c++; }
    }
    int incl = c;
    #pragma unroll
    for (int off = 1; off < 64; off <<= 1) {
        int v = __shfl_up(incl, off);
        if (lane >= off) incl += v;
    }
    if (lane == 63) wsum[w] = incl;
    __syncthreads();
    int wbase = 0;
    for (int i = 0; i < w; i++) wbase += wsum[i];
    int pos = offsets[e] + wbase + (incl - c);
    #pragma unroll
    for (int j = 0; j < 16; j++) {
        int t = t0 + j;
        if ((f0 >> j) & 1u)      { slot_token[pos] = t; slot_pos[t*2]   = pos; pos++; }
        else if ((f1 >> j) & 1u) { slot_token[pos] = t; slot_pos[t*2+1] = pos; pos++; }
    }
}

// ======= Phase A: expert gate/up (bid<4096) + shared gate/up (bid>=4096), K=1024, BK=64 =======
// Static double-buffer (no runtime-indexed LDS base!), 2x2 wave grid (wave=64x64).
// Bs interleaves gate/up in 32-row groups so each wave owns matching gate+up cols:
//   Bs rows [0:32)=gate[0:32), [32:64)=up[0:32), [64:96)=gate[32:64), [96:128)=up[32:64)
__global__ __launch_bounds__(256) void k_mlp1(
    const bf16* __restrict__ xb, const bf16* __restrict__ wgu,
    const bf16* __restrict__ wsg, const bf16* __restrict__ wsu,
    const int* __restrict__ slot_token, const int* __restrict__ offsets,
    bf16* __restrict__ hiddenE, bf16* __restrict__ sh_hid)
{
    int bid = blockIdx.x;
    bool expert = bid < 4096;
    int nt, mt, base, cnt;
    const bf16 *Bg, *Bu;
    bf16* outp; int nout;
    if (expert) {
        int e = bid >> 8; int r = bid & 255; nt = r & 7; mt = r >> 3;
        base = offsets[e]; cnt = offsets[e+1] - base;
        if (mt * 128 >= cnt) return;
        const bf16* wb = wgu + (size_t)e * (2 * MI_) * H_;
        Bg = wb + (size_t)(nt * 64) * H_;
        Bu = wb + (size_t)(MI_ + nt * 64) * H_;
        outp = hiddenE; nout = MI_;
    } else {
        int r = bid - 4096; nt = r & 31; mt = r >> 5;
        base = 0; cnt = T_;
        Bg = wsg + (size_t)(nt * 64) * H_;
        Bu = wsu + (size_t)(nt * 64) * H_;
        outp = sh_hid; nout = SI_;
    }

    __shared__ __align__(16) bf16 As0[128 * 64], Bs0[128 * 64];
    __shared__ __align__(16) bf16 As1[128 * 64], Bs1[128 * 64];

    int tid = threadIdx.x, w = tid >> 6, l = tid & 63;
    int lrow8 = l >> 3;                       // row within 8-row staging group
    int col_off = ((l & 7) ^ lrow8) * 8;      // inverse-swizzled global chunk

    const bf16* asrc[4];
    const bf16* bsrc[4];
    #pragma unroll
    for (int g = 0; g < 4; g++) {
        int rt = g * 32 + w * 8 + lrow8;      // row within 128-tile
        int s = mt * 128 + rt; if (s >= cnt) s = cnt - 1;
        asrc[g] = (expert ? xb + (size_t)slot_token[base + s] * H_
                          : xb + (size_t)s * H_) + col_off;
        int half = (rt >> 5) & 1;             // 0=gate, 1=up
        int gcol = ((rt >> 6) << 5) | (rt & 31);  // 0..63 within the 64-col pair group
        bsrc[g] = (half ? Bu : Bg) + (size_t)gcol * H_ + col_off;
    }

    int lr = l & 15, kq = l >> 4;
    int wm = w & 1, wn = w >> 1;              // 2x2 wave grid
    f32x4 acc[4][4];
    #pragma unroll
    for (int mi = 0; mi < 4; mi++)
        #pragma unroll
        for (int ni = 0; ni < 4; ni++) acc[mi][ni] = (f32x4){0.f, 0.f, 0.f, 0.f};

    auto STAGE = [&](bf16* Ad, bf16* Bd, int k0) {
        #pragma unroll
        for (int g = 0; g < 4; g++) {
            gload16(asrc[g] + k0, Ad + (g * 32 + w * 8) * 64);
            gload16(bsrc[g] + k0, Bd + (g * 32 + w * 8) * 64);
        }
    };
    auto COMPUTE = [&](const bf16* Ab, const bf16* Bb) {
        #pragma unroll
        for (int ks = 0; ks < 2; ks++) {
            int cl = ((ks * 4 + kq) ^ (lr & 7)) * 8;   // swizzled read chunk
            bf16x8 af[4], bfr[4];
            #pragma unroll
            for (int mi = 0; mi < 4; mi++)
                af[mi] = *reinterpret_cast<const bf16x8*>(&Ab[(wm * 64 + mi * 16 + lr) * 64 + cl]);
            #pragma unroll
            for (int ni = 0; ni < 4; ni++)
                bfr[ni] = *reinterpret_cast<const bf16x8*>(&Bb[(wn * 64 + ni * 16 + lr) * 64 + cl]);
            #pragma unroll
            for (int mi = 0; mi < 4; mi++)
                #pragma unroll
                for (int ni = 0; ni < 4; ni++)
                    acc[mi][ni] = __builtin_amdgcn_mfma_f32_16x16x32_bf16(af[mi], bfr[ni], acc[mi][ni], 0, 0, 0);
        }
    };

    STAGE(As0, Bs0, 0);
    __syncthreads();
    for (int k0 = 0; k0 < H_; k0 += 128) {
        STAGE(As1, Bs1, k0 + 64);     // flies during COMPUTE(As0)
        COMPUTE(As0, Bs0);
        __syncthreads();
        if (k0 + 128 < H_) STAGE(As0, Bs0, k0 + 128);  // flies during COMPUTE(As1)
        COMPUTE(As1, Bs1);
        __syncthreads();
    }

    // epilogue: row = ...kq*4+r, col = nt*64 + wn*32 + ni*16 + lr; gate=acc[][ni], up=acc[][ni+2]
    #pragma unroll
    for (int mi = 0; mi < 4; mi++)
        #pragma unroll
        for (int ni = 0; ni < 2; ni++)
            #pragma unroll
            for (int r = 0; r < 4; r++) {
                int row = mt * 128 + wm * 64 + mi * 16 + kq * 4 + r;
                if (row < cnt) {
                    int col = nt * 64 + wn * 32 + ni * 16 + lr;
                    float g = acc[mi][ni][r], u = acc[mi][ni + 2][r];
                    float hv = u * (g / (1.f + expf(-g)));
                    outp[(size_t)(base + row) * nout + col] = (bf16)hv;
                }
            }
}

// ======= Phase B: expert down (bid<4096, K=512) + shared down (bid>=4096, K=2048), BK=64 =======
// Same static-dbuf 2x2-wave structure, plain 128-col output tile.
__global__ __launch_bounds__(256) void k_mlp2(
    const bf16* __restrict__ hiddenE, const bf16* __restrict__ sh_hid,
    const bf16* __restrict__ wdn, const bf16* __restrict__ wsd,
    const int* __restrict__ offsets, const float* __restrict__ gate_s,
    bf16* __restrict__ eo, float* __restrict__ out)
{
    int bid = blockIdx.x;
    bool expert = bid < 4096;
    int nt, mt, base, cnt, KD;
    const bf16 *Ab, *B0;
    if (expert) {
        int e = bid >> 8; int r = bid & 255; nt = r & 7; mt = r >> 3;
        base = offsets[e]; cnt = offsets[e+1] - base;
        if (mt * 128 >= cnt) return;
        KD = MI_;
        Ab = hiddenE;
        B0 = wdn + (size_t)e * H_ * MI_ + (size_t)(nt * 128) * MI_;
    } else {
        int r = bid - 4096; nt = r & 7; mt = r >> 3;
        base = 0; cnt = T_; KD = SI_;
        Ab = sh_hid;
        B0 = wsd + (size_t)(nt * 128) * SI_;
    }

    __shared__ __align__(16) bf16 As0[128 * 64], Bs0[128 * 64];
    __shared__ __align__(16) bf16 As1[128 * 64], Bs1[128 * 64];

    int tid = threadIdx.x, w = tid >> 6, l = tid & 63;
    int lrow8 = l >> 3;
    int col_off = ((l & 7) ^ lrow8) * 8;

    const bf16* asrc[4];
    const bf16* bsrc[4];
    #pragma unroll
    for (int g = 0; g < 4; g++) {
        int rt = g * 32 + w * 8 + lrow8;
        int s = mt * 128 + rt; if (s >= cnt) s = cnt - 1;
        asrc[g] = Ab + (size_t)(base + s) * KD + col_off;
        bsrc[g] = B0 + (size_t)rt * KD + col_off;
    }

    int lr = l & 15, kq = l >> 4;
    int wm = w & 1, wn = w >> 1;
    f32x4 acc[4][4];
    #pragma unroll
    for (int mi = 0; mi < 4; mi++)
        #pragma unroll
        for (int ni = 0; ni < 4; ni++) acc[mi][ni] = (f32x4){0.f, 0.f, 0.f, 0.f};

    auto STAGE = [&](bf16* Ad, bf16* Bd, int k0) {
        #pragma unroll
        for (int g = 0; g < 4; g++) {
            gload16(asrc[g] + k0, Ad + (g * 32 + w * 8) * 64);
            gload16(bsrc[g] + k0, Bd + (g * 32 + w * 8) * 64);
        }
    };
    auto COMPUTE = [&](const bf16* Abuf, const bf16* Bbuf) {
        #pragma unroll
        for (int ks = 0; ks < 2; ks++) {
            int cl = ((ks * 4 + kq) ^ (lr & 7)) * 8;
            bf16x8 af[4], bfr[4];
            #pragma unroll
            for (int mi = 0; mi < 4; mi++)
                af[mi] = *reinterpret_cast<const bf16x8*>(&Abuf[(wm * 64 + mi * 16 + lr) * 64 + cl]);
            #pragma unroll
            for (int ni = 0; ni < 4; ni++)
                bfr[ni] = *reinterpret_cast<const bf16x8*>(&Bbuf[(wn * 64 + ni * 16 + lr) * 64 + cl]);
            #pragma unroll
            for (int mi = 0; mi < 4; mi++)
                #pragma unroll
                for (int ni = 0; ni < 4; ni++)
                    acc[mi][ni] = __builtin_amdgcn_mfma_f32_16x16x32_bf16(af[mi], bfr[ni], acc[mi][ni], 0, 0, 0);
        }
    };

    STAGE(As0, Bs0, 0);
    __syncthreads();
    for (int k0 = 0; k0 < KD; k0 += 128) {
        STAGE(As1, Bs1, k0 + 64);
        COMPUTE(As0, Bs0);
        __syncthreads();
        if (k0 + 128 < KD) STAGE(As0, Bs0, k0 + 128);
        COMPUTE(As1, Bs1);
        __syncthreads();
    }

    #pragma unroll
    for (int mi = 0; mi < 4; mi++)
        #pragma unroll
        for (int ni = 0; ni < 4; ni++)
            #pragma unroll
            for (int r = 0; r < 4; r++) {
                int row = mt * 128 + wm * 64 + mi * 16 + kq * 4 + r;
                if (row < cnt) {
                    int col = nt * 128 + wn * 64 + ni * 16 + lr;
                    float v = acc[mi][ni][r];
                    if (expert) eo[(size_t)(base + row) * H_ + col] = (bf16)v;
                    else        out[(size_t)row * H_ + col] = gate_s[row] * v;
                }
            }
}

// ---------------- combine: out += w0*eo[s0] + w1*eo[s1] ----------------
__global__ void k_combine(float* __restrict__ out, const bf16* __restrict__ eo,
                          const int* __restrict__ slot_pos, const float* __restrict__ top_w)
{
    int i = blockIdx.x * blockDim.x + threadIdx.x;
    int t = i >> 8;
    int q = (i & 255) * 4;
    int s0 = slot_pos[t*2], s1 = slot_pos[t*2+1];
    float w0 = top_w[t*2], w1 = top_w[t*2+1];
    bf16x4 e0 = *reinterpret_cast<const bf16x4*>(eo + (size_t)s0 * H_ + q);
    bf16x4 e1 = *reinterpret_cast<const bf16x4*>(eo + (size_t)s1 * H_ + q);
    float4* op = reinterpret_cast<float4*>(out) + i;
    float4 so = *op;
    float4 r;
    r.x = so.x + w0 * (float)e0[0] + w1 * (float)e1[0];
    r.y = so.y + w0 * (float)e0[1] + w1 * (float)e1[1];
    r.z = so.z + w0 * (float)e0[2] + w1 * (float)e1[2];
    r.w = so.w + w0 * (float)e0[3] + w1 * (float)e1[3];
    *op = r;
}

extern "C" void kernel_launch(void* const* d_in, const int* in_sizes, int n_in,
                              void* d_out, int out_size, void* d_ws, size_t ws_size,
                              hipStream_t stream) {
    const float* x    = (const float*)d_in[0];
    const float* rw   = (const float*)d_in[1];
    const float* wgu  = (const float*)d_in[2];
    const float* wdn  = (const float*)d_in[3];
    const float* wsg  = (const float*)d_in[4];
    const float* wsu  = (const float*)d_in[5];
    const float* wsd  = (const float*)d_in[6];
    const float* segw = (const float*)d_in[7];
    float* out    = (float*)d_out;
    float* logits = (float*)d_out + (size_t)T_ * H_;

    char* p = (char*)d_ws;
    bf16* xb      = (bf16*)p;  p += (size_t)T_ * H_ * 2;
    bf16* w_guT   = (bf16*)p;  p += (size_t)E_ * H_ * (2*MI_) * 2;
    bf16* w_dnT   = (bf16*)p;  p += (size_t)E_ * MI_ * H_ * 2;
    bf16* w_sgT   = (bf16*)p;  p += (size_t)H_ * SI_ * 2;
    bf16* w_suT   = (bf16*)p;  p += (size_t)H_ * SI_ * 2;
    bf16* w_sdT   = (bf16*)p;  p += (size_t)SI_ * H_ * 2;
    bf16* hiddenE = (bf16*)p;  p += (size_t)TK_ * MI_ * 2;
    bf16* sh_hid  = (bf16*)p;  p += (size_t)T_ * SI_ * 2;
    bf16* eo      = (bf16*)p;  p += (size_t)TK_ * H_ * 2;
    float* gate_s = (float*)p; p += (size_t)T_ * 4;
    int*  top_i   = (int*)p;   p += (size_t)T_ * 2 * 4;
    float* top_w  = (float*)p; p += (size_t)T_ * 2 * 4;
    int*  slot_pos= (int*)p;   p += (size_t)T_ * 2 * 4;
    int*  slot_tok= (int*)p;   p += (size_t)TK_ * 4;
    int*  offsets = (int*)p;   p += 17 * 4;

    // conversions + transposes
    k_convert<<<dim3(T_*H_/4/256), 256, 0, stream>>>(x, xb, T_*H_/4);
    k_transpose<<<dim3(32, 32, 16), dim3(32, 8), 0, stream>>>(wgu, w_guT, 1024, 1024);
    k_transpose<<<dim3(32, 16, 16), dim3(32, 8), 0, stream>>>(wdn, w_dnT, 512, 1024);
    k_transpose<<<dim3(64, 32, 1),  dim3(32, 8), 0, stream>>>(wsg, w_sgT, 1024, 2048);
    k_transpose<<<dim3(64, 32, 1),  dim3(32, 8), 0, stream>>>(wsu, w_suT, 1024, 2048);
    k_transpose<<<dim3(32, 64, 1),  dim3(32, 8), 0, stream>>>(wsd, w_sdT, 2048, 1024);

    // routing (atomic-free)
    k_router<<<dim3(T_/4), 256, 0, stream>>>(x, rw, segw, logits, top_i, top_w, gate_s);
    k_count<<<dim3(1), 256, 0, stream>>>(top_i, offsets);
    k_fillscan<<<dim3(E_), 256, 0, stream>>>(top_i, offsets, slot_tok, slot_pos);

    // phase A: all gate/up GEMMs in one launch (expert blocks + shared blocks)
    k_mlp1<<<dim3(4096 + 1024), 256, 0, stream>>>(xb, w_guT, w_sgT, w_suT, slot_tok, offsets, hiddenE, sh_hid);
    // phase B: all down GEMMs in one launch
    k_mlp2<<<dim3(4096 + 256), 256, 0, stream>>>(hiddenE, sh_hid, w_dnT, w_sdT, offsets, gate_s, eo, out);

    // combine expert contributions into d_out
    k_combine<<<dim3(T_*256/256), 256, 0, stream>>>(out, eo, slot_pos, top_w);
}